// Round 13
// baseline (813.137 us; speedup 1.0000x reference)
//
#include <hip/hip_runtime.h>
#include <hip/hip_bf16.h>

// ---------------------------------------------------------------------------
// MoE layer: router (softmax, top-2) + 16 experts (D=2048 -> H=1024 -> D) +
// shared expert (D -> F=1024 -> D), gate-weighted combine, aux stats.
// R13: T4 minimal on the proven R10 GEMM: triple-buffered K-loop with
//      counted vmcnt(4) + raw s_barrier (no __syncthreads vmcnt0 drain).
//      Each HBM stage now has 2 compute phases to land instead of 1 —
//      attacks the ~50% barrier-stall idle (MfmaUtil 22 / VALU 25 / occ 32).
//      Grid back to plain 3D (R11/R12 showed swizzle is a wash when balanced;
//      FETCH doesn't bind time). Router-fused x cast kept.
// ---------------------------------------------------------------------------

#define N_TOK 8192
#define DDIM  2048
#define NEXP  16
#define HDIM  1024
#define FDIM  1024
#define NASSIGN (N_TOK * 2)
#define NROWS (NASSIGN + N_TOK)      // 24576: expert assignments + shared rows

typedef __attribute__((ext_vector_type(8))) short bf16x8;
typedef __attribute__((ext_vector_type(4))) float f32x4;
typedef __attribute__((ext_vector_type(8))) unsigned short u16x8;
typedef __attribute__((ext_vector_type(4))) unsigned short u16x4;

__device__ inline unsigned short f2bf(float f) {
    unsigned int u = __builtin_bit_cast(unsigned int, f);
    u += 0x7FFFu + ((u >> 16) & 1u);           // RNE (finite inputs only)
    return (unsigned short)(u >> 16);
}

__device__ inline float bf2f(unsigned short h) {
    return __builtin_bit_cast(float, (unsigned int)h << 16);
}

__device__ inline float gelu_f(float v) {
    return 0.5f * v * (1.0f + erff(v * 0.7071067811865475f));
}

__device__ inline void gld16(void* lds, const void* g) {
    __builtin_amdgcn_global_load_lds(
        (const __attribute__((address_space(1))) unsigned int*)g,
        (__attribute__((address_space(3))) unsigned int*)lds, 16, 0, 0);
}

// ---------------------------------------------------------------------------
__global__ __launch_bounds__(256) void zero_small(float* imp) {
    if (threadIdx.x < NEXP) imp[threadIdx.x] = 0.0f;
}

// [R][C] fp32 -> [C][R] bf16, 64x64 LDS tiles, batched over blockIdx.z
template <int R, int C>
__global__ __launch_bounds__(256) void transpose_cast(const float* __restrict__ src,
                                                      unsigned short* __restrict__ dst) {
    __shared__ unsigned short t[64][66];
    const size_t zoff = (size_t)blockIdx.z * R * C;
    src += zoff; dst += zoff;
    const int r0 = blockIdx.y * 64, c0 = blockIdx.x * 64;
    const int tid = threadIdx.x;
    const int cr = tid >> 4;            // 0..15
    const int cc4 = (tid & 15) * 4;
#pragma unroll
    for (int it = 0; it < 4; ++it) {
        int row = cr + it * 16;
        const float4 v = *(const float4*)(src + (size_t)(r0 + row) * C + c0 + cc4);
        t[row][cc4 + 0] = f2bf(v.x); t[row][cc4 + 1] = f2bf(v.y);
        t[row][cc4 + 2] = f2bf(v.z); t[row][cc4 + 3] = f2bf(v.w);
    }
    __syncthreads();
#pragma unroll
    for (int it = 0; it < 4; ++it) {
        int cc = cr + it * 16;
        u16x4 o;
#pragma unroll
        for (int j = 0; j < 4; ++j) o[j] = t[cc4 + j][cc];
        *(u16x4*)(dst + (size_t)(c0 + cc) * R + r0 + cc4) = o;
    }
}

// ---------------------------------------------------------------------------
// Router: one wave per token. logits = x@Wr (16), gate = x@Wg; softmax; top-2.
// Also writes xb = bf16(x) in the same pass (each element read exactly once).
__global__ __launch_bounds__(256) void router_kernel(
    const float* __restrict__ x, const float* __restrict__ Wr, const float* __restrict__ Wg,
    unsigned short* __restrict__ xb,
    float* __restrict__ gsh, int* __restrict__ t2i, float* __restrict__ t2v,
    float* __restrict__ imp) {
    __shared__ float simp[NEXP];
    const int tid = threadIdx.x, lane = tid & 63, w = tid >> 6;
    if (tid < NEXP) simp[tid] = 0.0f;
    __syncthreads();
    const int n = blockIdx.x * 4 + w;
    const float* xr = x + (size_t)n * DDIM;
    unsigned short* xbr = xb + (size_t)n * DDIM;
    float acc[NEXP];
#pragma unroll
    for (int e = 0; e < NEXP; ++e) acc[e] = 0.0f;
    float ag = 0.0f;
    for (int j = 0; j < DDIM / 64; ++j) {
        int d = lane + j * 64;
        float xv = xr[d];
        xbr[d] = f2bf(xv);
        const float* wr = Wr + (size_t)d * NEXP;
#pragma unroll
        for (int e = 0; e < NEXP; ++e) acc[e] = fmaf(xv, wr[e], acc[e]);
        ag = fmaf(xv, Wg[d], ag);
    }
#pragma unroll
    for (int off = 32; off; off >>= 1) {
#pragma unroll
        for (int e = 0; e < NEXP; ++e) acc[e] += __shfl_xor(acc[e], off);
        ag += __shfl_xor(ag, off);
    }
    if (lane == 0) {
        float mx = acc[0];
#pragma unroll
        for (int e = 1; e < NEXP; ++e) mx = fmaxf(mx, acc[e]);
        float p[NEXP], s = 0.0f;
#pragma unroll
        for (int e = 0; e < NEXP; ++e) { p[e] = expf(acc[e] - mx); s += p[e]; }
        const float inv = 1.0f / s;
        int i1 = 0; float v1 = -1.0f;
#pragma unroll
        for (int e = 0; e < NEXP; ++e) {
            p[e] *= inv;
            if (p[e] > v1) { v1 = p[e]; i1 = e; }
        }
        int i2 = 0; float v2 = -1.0f;
#pragma unroll
        for (int e = 0; e < NEXP; ++e) {
            if (e != i1 && p[e] > v2) { v2 = p[e]; i2 = e; }
        }
        t2i[2 * n] = i1; t2i[2 * n + 1] = i2;
        t2v[2 * n] = v1; t2v[2 * n + 1] = v2;
        gsh[n] = 1.0f / (1.0f + expf(-ag));
#pragma unroll
        for (int e = 0; e < NEXP; ++e) atomicAdd(&simp[e], p[e]);
    }
    __syncthreads();
    if (tid < NEXP) unsafeAtomicAdd(&imp[tid], simp[tid]);
}

// Single block: histogram counts, exclusive scan -> offsets, aux outputs, fill=0
__global__ __launch_bounds__(256) void scan_finalize(
    const int* __restrict__ t2i, const float* __restrict__ imp,
    int* __restrict__ offs, int* __restrict__ fill, float* __restrict__ out_tail) {
    __shared__ int hist[NEXP];
    const int tid = threadIdx.x;
    if (tid < NEXP) hist[tid] = 0;
    __syncthreads();
    for (int i = tid; i < NASSIGN; i += 256) atomicAdd(&hist[t2i[i]], 1);
    __syncthreads();
    if (tid == 0) {
        int o = 0;
        for (int e = 0; e < NEXP; ++e) { offs[e] = o; o += hist[e]; }
        offs[NEXP] = o;              // = NASSIGN
        offs[NEXP + 1] = NROWS;      // shared-expert group (group 16)
    }
    if (tid < NEXP) {
        fill[tid] = 0;
        out_tail[tid] = imp[tid] * (1.0f / (float)N_TOK);
        out_tail[NEXP + tid] = (float)hist[tid] / (float)NASSIGN;
    }
}

// also records t2pos (token,k)->slot, and fills the shared-group tail rows.
// Shared group's gate = gsh (linear fold: gsh*(h@W2s) == (gsh*h)@W2s).
__global__ __launch_bounds__(256) void build_assign(
    const int* __restrict__ t2i, const float* __restrict__ t2v,
    const int* __restrict__ offs, int* __restrict__ fill,
    const float* __restrict__ gsh,
    int* __restrict__ atok, float* __restrict__ agate, int* __restrict__ t2pos) {
    const int n = blockIdx.x * 256 + threadIdx.x;
#pragma unroll
    for (int k = 0; k < 2; ++k) {
        int e = t2i[2 * n + k];
        int pos = offs[e] + atomicAdd(&fill[e], 1);
        atok[pos] = n;
        agate[pos] = t2v[2 * n + k];
        t2pos[2 * n + k] = pos;
    }
    atok[NASSIGN + n] = n;           // shared group: identity gather
    agate[NASSIGN + n] = gsh[n];     // gsh applied via L1 gate (linear)
}

// y[n][d] = contrib[p0][d] + contrib[p1][d] + contrib[shared(n)][d]
__global__ __launch_bounds__(256) void combine_kernel(
    const unsigned short* __restrict__ contrib, const int* __restrict__ t2pos,
    float* __restrict__ y) {
    const int gi = blockIdx.x * 256 + threadIdx.x;      // group of 8 floats
    const int n = gi >> 8;                              // DDIM/8 = 256 groups/row
    const int d8 = (gi & 255) * 8;
    const int p0 = t2pos[2 * n], p1 = t2pos[2 * n + 1];
    u16x8 a = *(const u16x8*)(contrib + (size_t)p0 * DDIM + d8);
    u16x8 b = *(const u16x8*)(contrib + (size_t)p1 * DDIM + d8);
    u16x8 c = *(const u16x8*)(contrib + (size_t)(NASSIGN + n) * DDIM + d8);
    float4 y0, y1;
    y0.x = bf2f(a[0]) + bf2f(b[0]) + bf2f(c[0]);
    y0.y = bf2f(a[1]) + bf2f(b[1]) + bf2f(c[1]);
    y0.z = bf2f(a[2]) + bf2f(b[2]) + bf2f(c[2]);
    y0.w = bf2f(a[3]) + bf2f(b[3]) + bf2f(c[3]);
    y1.x = bf2f(a[4]) + bf2f(b[4]) + bf2f(c[4]);
    y1.y = bf2f(a[5]) + bf2f(b[5]) + bf2f(c[5]);
    y1.z = bf2f(a[6]) + bf2f(b[6]) + bf2f(c[6]);
    y1.w = bf2f(a[7]) + bf2f(b[7]) + bf2f(c[7]);
    float* yr = y + (size_t)n * DDIM + d8;
    *(float4*)yr = y0;
    *(float4*)(yr + 4) = y1;
}

// ---------------------------------------------------------------------------
// Grouped GEMM: C[M][NC] = A[M][KD] * B^T[NC][KD], bf16 in, fp32 accum.
// R10 geometry (128x128, BK=32, 4 waves, proven 513 TF) with a T4 pipeline:
// THREE LDS buffers (48 KiB), stage(t+2) issued each iteration, iteration
// ends with s_waitcnt vmcnt(4) (keep the 4 newest loads in flight) + RAW
// s_barrier (no __syncthreads vmcnt(0) drain). Each stage gets ~2 compute
// phases to cover HBM latency. Per-wave vmcnt is sound: every wave waits its
// own 4 t+1-loads before the barrier, so after the barrier the whole tile
// t+1 is resident. WAR: buf b is overwritten 2 iterations after its compute,
// separated by a barrier (all reads landed in-wave before that barrier).
// Tail: vmcnt(0) at t=NT-2; no barrier after t=NT-1.
// MODE 0: L1 (A = gathered xb, out = f2bf(gelu(v)*gate) -> hb[NROWS][HDIM])
// MODE 1: L2 (A = hb rows,     out = f2bf(v)            -> contrib[NROWS][DDIM])
template <int MODE>
__global__ __launch_bounds__(256, 3) void gemm128(
    const unsigned short* __restrict__ A, const unsigned short* __restrict__ B,
    unsigned short* __restrict__ out,
    const int* __restrict__ offs, const int* __restrict__ atok,
    const float* __restrict__ agate) {
    constexpr int KD = MODE == 0 ? DDIM : HDIM;
    constexpr int NC = MODE == 0 ? HDIM : DDIM;
    constexpr int NT = KD / 32;                  // K-steps (64 or 32)
    const int e = blockIdx.z;
    const int m0 = offs[e];
    const int mE = offs[e + 1] - m0;
    const int tm = blockIdx.y;
    if (tm * 128 >= mE) return;
    const int n0 = blockIdx.x * 128;

    __shared__ __align__(16) unsigned short As_[3][128 * 32];   // 8 KiB each
    __shared__ __align__(16) unsigned short Bs_[3][128 * 32];   // total 48 KiB

    const int tid = threadIdx.x, lane = tid & 63;
    const int wid = tid >> 6, wm = wid >> 1, wn = wid & 1;

    // ---- staging descriptors (pre-swizzled global sources) ----
    // chunk c in 0..511: row = c>>2 (0..127), slot = c&3 (16B within 64B row)
    const unsigned short* sA[2];
    const unsigned short* sB[2];
    int dOff[2];
#pragma unroll
    for (int it = 0; it < 2; ++it) {
        int c = tid + it * 256;
        int row = c >> 2, slot = c & 3;
        int ksw = (slot ^ ((row >> 1) & 3)) * 8;   // pre-swizzled k-chunk
        int arow = tm * 128 + row; arow = arow < mE ? arow : mE - 1;
        if (MODE == 0)
            sA[it] = A + (size_t)atok[m0 + arow] * KD + ksw;
        else
            sA[it] = A + (size_t)(m0 + arow) * KD + ksw;
        sB[it] = B + (size_t)e * KD * NC + (size_t)(n0 + row) * KD + ksw;
        dOff[it] = c * 16;
    }

    f32x4 acc[4][4] = {};

    auto stage = [&](int b, int t) {
        const int kk = t * 32;
        gld16((char*)As_[b] + dOff[0], sA[0] + kk);
        gld16((char*)As_[b] + dOff[1], sA[1] + kk);
        gld16((char*)Bs_[b] + dOff[0], sB[0] + kk);
        gld16((char*)Bs_[b] + dOff[1], sB[1] + kk);
    };
    auto compute = [&](int b) {
        const int c16 = lane & 15, q = lane >> 4;
        bf16x8 av[4], bv[4];
#pragma unroll
        for (int mi = 0; mi < 4; ++mi) {
            int r = wm * 64 + mi * 16 + c16;
            int s = q ^ ((r >> 1) & 3);
            av[mi] = *(const bf16x8*)((const char*)As_[b] + r * 64 + s * 16);
        }
#pragma unroll
        for (int ni = 0; ni < 4; ++ni) {
            int r = wn * 64 + ni * 16 + c16;
            int s = q ^ ((r >> 1) & 3);
            bv[ni] = *(const bf16x8*)((const char*)Bs_[b] + r * 64 + s * 16);
        }
#pragma unroll
        for (int mi = 0; mi < 4; ++mi)
#pragma unroll
            for (int ni = 0; ni < 4; ++ni)
                acc[mi][ni] = __builtin_amdgcn_mfma_f32_16x16x32_bf16(
                    av[mi], bv[ni], acc[mi][ni], 0, 0, 0);
    };

    // prologue: tiles 0,1 -> bufs 0,1; wait tile0 (own 4 oldest), barrier
    stage(0, 0);
    stage(1, 1);
    asm volatile("s_waitcnt vmcnt(4)" ::: "memory");
    __builtin_amdgcn_sched_barrier(0);
    __builtin_amdgcn_s_barrier();
    __builtin_amdgcn_sched_barrier(0);

    int b = 0, bn = 2;
#pragma unroll 1
    for (int t = 0; t < NT; ++t) {
        if (t + 2 < NT) {
            stage(bn, t + 2);
            compute(b);
            asm volatile("s_waitcnt vmcnt(4)" ::: "memory");
            __builtin_amdgcn_sched_barrier(0);
            __builtin_amdgcn_s_barrier();
            __builtin_amdgcn_sched_barrier(0);
        } else if (t + 1 < NT) {
            compute(b);
            asm volatile("s_waitcnt vmcnt(0)" ::: "memory");
            __builtin_amdgcn_sched_barrier(0);
            __builtin_amdgcn_s_barrier();
            __builtin_amdgcn_sched_barrier(0);
        } else {
            compute(b);
        }
        b = (b == 2) ? 0 : b + 1;
        bn = (bn == 2) ? 0 : bn + 1;
    }

    // epilogue: C/D layout col = lane&15, row = (lane>>4)*4 + reg
    const int col = lane & 15, r4 = (lane >> 4) * 4;
#pragma unroll
    for (int mi = 0; mi < 4; ++mi) {
#pragma unroll
        for (int r = 0; r < 4; ++r) {
            int grow = tm * 128 + wm * 64 + mi * 16 + r4 + r;
            if (grow >= mE) continue;
            float gate = (MODE == 0) ? agate[m0 + grow] : 0.0f;
#pragma unroll
            for (int ni = 0; ni < 4; ++ni) {
                int gcol = n0 + wn * 64 + ni * 16 + col;
                float v = acc[mi][ni][r];
                if (MODE == 0)
                    out[(size_t)(m0 + grow) * NC + gcol] = f2bf(gelu_f(v) * gate);
                else
                    out[(size_t)(m0 + grow) * NC + gcol] = f2bf(v);
            }
        }
    }
}

// ---------------------------------------------------------------------------
extern "C" void kernel_launch(void* const* d_in, const int* in_sizes, int n_in,
                              void* d_out, int out_size, void* d_ws, size_t ws_size,
                              hipStream_t stream) {
    const float* x   = (const float*)d_in[0];
    const float* Wr  = (const float*)d_in[1];
    const float* Wg  = (const float*)d_in[2];
    const float* W1  = (const float*)d_in[3];
    const float* W2  = (const float*)d_in[4];
    const float* W1s = (const float*)d_in[5];
    const float* W2s = (const float*)d_in[6];
    float* out = (float*)d_out;

    char* ws = (char*)d_ws;
    size_t off = 0;
    auto carve = [&](size_t bytes) { char* p = ws + off; off += (bytes + 255) & ~(size_t)255; return p; };
    // NOTE: contrib (NROWS x DDIM bf16 = 96 MiB) aliases [xb, w1all] (100 MiB),
    // both dead after gemm128<0>; stream order serializes the reuse.
    unsigned short* xb    = (unsigned short*)carve((size_t)N_TOK * DDIM * 2);            // 32 MiB
    unsigned short* w1all = (unsigned short*)carve((size_t)(NEXP + 1) * DDIM * HDIM * 2);// 68 MiB
    unsigned short* w2all = (unsigned short*)carve((size_t)(NEXP + 1) * HDIM * DDIM * 2);// 68 MiB
    unsigned short* hb    = (unsigned short*)carve((size_t)NROWS * HDIM * 2);            // 48 MiB
    float* gsh            = (float*)carve((size_t)N_TOK * 4);
    int* t2i              = (int*)carve((size_t)N_TOK * 2 * 4);
    float* t2v            = (float*)carve((size_t)N_TOK * 2 * 4);
    int* atok             = (int*)carve((size_t)NROWS * 4);
    float* agate          = (float*)carve((size_t)NROWS * 4);
    int* t2pos            = (int*)carve((size_t)NASSIGN * 4);
    float* imp            = (float*)carve(256);
    int* offs             = (int*)carve(256);
    int* fill             = (int*)carve(256);
    if (ws_size < off) return;   // fail loudly (output stays invalid)

    unsigned short* contrib = (unsigned short*)ws;   // alias over xb+w1all

    float* out_tail = out + (size_t)N_TOK * DDIM;

    hipLaunchKernelGGL(zero_small, dim3(1), dim3(256), 0, stream, imp);
    // weights, transposed to B^T[NC][KD], shared expert appended as group 16
    hipLaunchKernelGGL((transpose_cast<DDIM, HDIM>), dim3(HDIM / 64, DDIM / 64, NEXP), dim3(256), 0, stream, W1, w1all);
    hipLaunchKernelGGL((transpose_cast<DDIM, HDIM>), dim3(HDIM / 64, DDIM / 64, 1), dim3(256), 0, stream,
                       W1s, w1all + (size_t)NEXP * DDIM * HDIM);
    hipLaunchKernelGGL((transpose_cast<HDIM, DDIM>), dim3(DDIM / 64, HDIM / 64, NEXP), dim3(256), 0, stream, W2, w2all);
    hipLaunchKernelGGL((transpose_cast<HDIM, DDIM>), dim3(DDIM / 64, HDIM / 64, 1), dim3(256), 0, stream,
                       W2s, w2all + (size_t)NEXP * HDIM * DDIM);
    // router also writes xb (bf16 cast of x, one pass)
    hipLaunchKernelGGL(router_kernel, dim3(N_TOK / 4), dim3(256), 0, stream, x, Wr, Wg, xb, gsh, t2i, t2v, imp);
    hipLaunchKernelGGL(scan_finalize, dim3(1), dim3(256), 0, stream, t2i, imp, offs, fill, out_tail);
    hipLaunchKernelGGL(build_assign, dim3(N_TOK / 256), dim3(256), 0, stream, t2i, t2v, offs, fill, gsh, atok, agate, t2pos);

    // grouped L1 (17 groups incl. shared): xb -> hb
    hipLaunchKernelGGL((gemm128<0>), dim3(HDIM / 128, N_TOK / 128, NEXP + 1), dim3(256), 0, stream,
                       xb, w1all, hb, offs, atok, agate);
    // grouped L2: hb -> contrib (overwrites xb/w1all region)
    hipLaunchKernelGGL((gemm128<1>), dim3(DDIM / 128, N_TOK / 128, NEXP + 1), dim3(256), 0, stream,
                       hb, w2all, contrib, offs, atok, agate);
    // y[n] = contrib[p0] + contrib[p1] + contrib[shared] (gsh folded into L1 gate)
    hipLaunchKernelGGL(combine_kernel, dim3(N_TOK * DDIM / 8 / 256), dim3(256), 0, stream,
                       contrib, t2pos, out);
}

// Round 14
// 600.463 us; speedup vs baseline: 1.3542x; 1.3542x over previous
//
#include <hip/hip_runtime.h>
#include <hip/hip_bf16.h>

// ---------------------------------------------------------------------------
// MoE layer: router (softmax, top-2) + 16 experts (D=2048 -> H=1024 -> D) +
// shared expert (D -> F=1024 -> D), gate-weighted combine, aux stats.
// R14: CONSOLIDATION. GEMM = R10's proven kernel verbatim (128x128xBK32,
//      4 waves, 2-phase dbuf, __syncthreads, (256,4): 513 TF, best of 9
//      GEMM variants measured R4-R13). Structural experiments closed out:
//      256^2 family (R6/R8/R9) loses to occupancy; asm vmcnt pipelines
//      (R13) and sched pinning lose to compiler scheduling (guide m141);
//      XCD swizzle is a wash when balanced (R12). Kept aux wins: router-
//      fused x cast, gsh folded into shared-group gate, bf16 contrib +
//      combine. New: 4 transpose launches merged into 2 (z=17).
// ---------------------------------------------------------------------------

#define N_TOK 8192
#define DDIM  2048
#define NEXP  16
#define HDIM  1024
#define FDIM  1024
#define NASSIGN (N_TOK * 2)
#define NROWS (NASSIGN + N_TOK)      // 24576: expert assignments + shared rows

typedef __attribute__((ext_vector_type(8))) short bf16x8;
typedef __attribute__((ext_vector_type(4))) float f32x4;
typedef __attribute__((ext_vector_type(8))) unsigned short u16x8;
typedef __attribute__((ext_vector_type(4))) unsigned short u16x4;

__device__ inline unsigned short f2bf(float f) {
    unsigned int u = __builtin_bit_cast(unsigned int, f);
    u += 0x7FFFu + ((u >> 16) & 1u);           // RNE (finite inputs only)
    return (unsigned short)(u >> 16);
}

__device__ inline float bf2f(unsigned short h) {
    return __builtin_bit_cast(float, (unsigned int)h << 16);
}

__device__ inline float gelu_f(float v) {
    return 0.5f * v * (1.0f + erff(v * 0.7071067811865475f));
}

__device__ inline void gld16(void* lds, const void* g) {
    __builtin_amdgcn_global_load_lds(
        (const __attribute__((address_space(1))) unsigned int*)g,
        (__attribute__((address_space(3))) unsigned int*)lds, 16, 0, 0);
}

// ---------------------------------------------------------------------------
__global__ __launch_bounds__(256) void zero_small(float* imp) {
    if (threadIdx.x < NEXP) imp[threadIdx.x] = 0.0f;
}

// [R][C] fp32 -> [C][R] bf16, 64x64 LDS tiles. z in [0,NEXP]: z<NEXP reads
// srcW + z*R*C (expert weights), z==NEXP reads srcS (shared expert weight).
template <int R, int C>
__global__ __launch_bounds__(256) void transpose_cast(const float* __restrict__ srcW,
                                                      const float* __restrict__ srcS,
                                                      unsigned short* __restrict__ dst) {
    __shared__ unsigned short t[64][66];
    const int z = blockIdx.z;
    const float* src = (z < NEXP) ? srcW + (size_t)z * R * C : srcS;
    dst += (size_t)z * R * C;
    const int r0 = blockIdx.y * 64, c0 = blockIdx.x * 64;
    const int tid = threadIdx.x;
    const int cr = tid >> 4;            // 0..15
    const int cc4 = (tid & 15) * 4;
#pragma unroll
    for (int it = 0; it < 4; ++it) {
        int row = cr + it * 16;
        const float4 v = *(const float4*)(src + (size_t)(r0 + row) * C + c0 + cc4);
        t[row][cc4 + 0] = f2bf(v.x); t[row][cc4 + 1] = f2bf(v.y);
        t[row][cc4 + 2] = f2bf(v.z); t[row][cc4 + 3] = f2bf(v.w);
    }
    __syncthreads();
#pragma unroll
    for (int it = 0; it < 4; ++it) {
        int cc = cr + it * 16;
        u16x4 o;
#pragma unroll
        for (int j = 0; j < 4; ++j) o[j] = t[cc4 + j][cc];
        *(u16x4*)(dst + (size_t)(c0 + cc) * R + r0 + cc4) = o;
    }
}

// ---------------------------------------------------------------------------
// Router: one wave per token. logits = x@Wr (16), gate = x@Wg; softmax; top-2.
// Also writes xb = bf16(x) in the same pass (each element read exactly once).
__global__ __launch_bounds__(256) void router_kernel(
    const float* __restrict__ x, const float* __restrict__ Wr, const float* __restrict__ Wg,
    unsigned short* __restrict__ xb,
    float* __restrict__ gsh, int* __restrict__ t2i, float* __restrict__ t2v,
    float* __restrict__ imp) {
    __shared__ float simp[NEXP];
    const int tid = threadIdx.x, lane = tid & 63, w = tid >> 6;
    if (tid < NEXP) simp[tid] = 0.0f;
    __syncthreads();
    const int n = blockIdx.x * 4 + w;
    const float* xr = x + (size_t)n * DDIM;
    unsigned short* xbr = xb + (size_t)n * DDIM;
    float acc[NEXP];
#pragma unroll
    for (int e = 0; e < NEXP; ++e) acc[e] = 0.0f;
    float ag = 0.0f;
    for (int j = 0; j < DDIM / 64; ++j) {
        int d = lane + j * 64;
        float xv = xr[d];
        xbr[d] = f2bf(xv);
        const float* wr = Wr + (size_t)d * NEXP;
#pragma unroll
        for (int e = 0; e < NEXP; ++e) acc[e] = fmaf(xv, wr[e], acc[e]);
        ag = fmaf(xv, Wg[d], ag);
    }
#pragma unroll
    for (int off = 32; off; off >>= 1) {
#pragma unroll
        for (int e = 0; e < NEXP; ++e) acc[e] += __shfl_xor(acc[e], off);
        ag += __shfl_xor(ag, off);
    }
    if (lane == 0) {
        float mx = acc[0];
#pragma unroll
        for (int e = 1; e < NEXP; ++e) mx = fmaxf(mx, acc[e]);
        float p[NEXP], s = 0.0f;
#pragma unroll
        for (int e = 0; e < NEXP; ++e) { p[e] = expf(acc[e] - mx); s += p[e]; }
        const float inv = 1.0f / s;
        int i1 = 0; float v1 = -1.0f;
#pragma unroll
        for (int e = 0; e < NEXP; ++e) {
            p[e] *= inv;
            if (p[e] > v1) { v1 = p[e]; i1 = e; }
        }
        int i2 = 0; float v2 = -1.0f;
#pragma unroll
        for (int e = 0; e < NEXP; ++e) {
            if (e != i1 && p[e] > v2) { v2 = p[e]; i2 = e; }
        }
        t2i[2 * n] = i1; t2i[2 * n + 1] = i2;
        t2v[2 * n] = v1; t2v[2 * n + 1] = v2;
        gsh[n] = 1.0f / (1.0f + expf(-ag));
#pragma unroll
        for (int e = 0; e < NEXP; ++e) atomicAdd(&simp[e], p[e]);
    }
    __syncthreads();
    if (tid < NEXP) unsafeAtomicAdd(&imp[tid], simp[tid]);
}

// Single block: histogram counts, exclusive scan -> offsets, aux outputs, fill=0
__global__ __launch_bounds__(256) void scan_finalize(
    const int* __restrict__ t2i, const float* __restrict__ imp,
    int* __restrict__ offs, int* __restrict__ fill, float* __restrict__ out_tail) {
    __shared__ int hist[NEXP];
    const int tid = threadIdx.x;
    if (tid < NEXP) hist[tid] = 0;
    __syncthreads();
    for (int i = tid; i < NASSIGN; i += 256) atomicAdd(&hist[t2i[i]], 1);
    __syncthreads();
    if (tid == 0) {
        int o = 0;
        for (int e = 0; e < NEXP; ++e) { offs[e] = o; o += hist[e]; }
        offs[NEXP] = o;              // = NASSIGN
        offs[NEXP + 1] = NROWS;      // shared-expert group (group 16)
    }
    if (tid < NEXP) {
        fill[tid] = 0;
        out_tail[tid] = imp[tid] * (1.0f / (float)N_TOK);
        out_tail[NEXP + tid] = (float)hist[tid] / (float)NASSIGN;
    }
}

// also records t2pos (token,k)->slot, and fills the shared-group tail rows.
// Shared group's gate = gsh (linear fold: gsh*(h@W2s) == (gsh*h)@W2s).
__global__ __launch_bounds__(256) void build_assign(
    const int* __restrict__ t2i, const float* __restrict__ t2v,
    const int* __restrict__ offs, int* __restrict__ fill,
    const float* __restrict__ gsh,
    int* __restrict__ atok, float* __restrict__ agate, int* __restrict__ t2pos) {
    const int n = blockIdx.x * 256 + threadIdx.x;
#pragma unroll
    for (int k = 0; k < 2; ++k) {
        int e = t2i[2 * n + k];
        int pos = offs[e] + atomicAdd(&fill[e], 1);
        atok[pos] = n;
        agate[pos] = t2v[2 * n + k];
        t2pos[2 * n + k] = pos;
    }
    atok[NASSIGN + n] = n;           // shared group: identity gather
    agate[NASSIGN + n] = gsh[n];     // gsh applied via L1 gate (linear)
}

// y[n][d] = contrib[p0][d] + contrib[p1][d] + contrib[shared(n)][d]
__global__ __launch_bounds__(256) void combine_kernel(
    const unsigned short* __restrict__ contrib, const int* __restrict__ t2pos,
    float* __restrict__ y) {
    const int gi = blockIdx.x * 256 + threadIdx.x;      // group of 8 floats
    const int n = gi >> 8;                              // DDIM/8 = 256 groups/row
    const int d8 = (gi & 255) * 8;
    const int p0 = t2pos[2 * n], p1 = t2pos[2 * n + 1];
    u16x8 a = *(const u16x8*)(contrib + (size_t)p0 * DDIM + d8);
    u16x8 b = *(const u16x8*)(contrib + (size_t)p1 * DDIM + d8);
    u16x8 c = *(const u16x8*)(contrib + (size_t)(NASSIGN + n) * DDIM + d8);
    float4 y0, y1;
    y0.x = bf2f(a[0]) + bf2f(b[0]) + bf2f(c[0]);
    y0.y = bf2f(a[1]) + bf2f(b[1]) + bf2f(c[1]);
    y0.z = bf2f(a[2]) + bf2f(b[2]) + bf2f(c[2]);
    y0.w = bf2f(a[3]) + bf2f(b[3]) + bf2f(c[3]);
    y1.x = bf2f(a[4]) + bf2f(b[4]) + bf2f(c[4]);
    y1.y = bf2f(a[5]) + bf2f(b[5]) + bf2f(c[5]);
    y1.z = bf2f(a[6]) + bf2f(b[6]) + bf2f(c[6]);
    y1.w = bf2f(a[7]) + bf2f(b[7]) + bf2f(c[7]);
    float* yr = y + (size_t)n * DDIM + d8;
    *(float4*)yr = y0;
    *(float4*)(yr + 4) = y1;
}

// ---------------------------------------------------------------------------
// Grouped GEMM: C[M][NC] = A[M][KD] * B^T[NC][KD], bf16 in, fp32 accum.
// R10's proven kernel VERBATIM: 128x128 tile, BK=32, 4 waves (2Mx2N),
// 2-phase double-buffered K-loop (stage next buf BEFORE compute of current,
// one __syncthreads per buffer), 32 KiB LDS, __launch_bounds__(256,4)
// (VGPR 60 + 64 AGPR fits the 128-reg/4-wave budget; no spill; 513 TF).
// Swizzle (0 conflicts measured): 16B slot s of row r (64B rows) holds
// k-chunk s^((r>>1)&3); pre-swizzled global source, read at slot q^((r>>1)&3).
// MODE 0: L1 (A = gathered xb, out = f2bf(gelu(v)*gate) -> hb[NROWS][HDIM])
// MODE 1: L2 (A = hb rows,     out = f2bf(v)            -> contrib[NROWS][DDIM])
template <int MODE>
__global__ __launch_bounds__(256, 4) void gemm128(
    const unsigned short* __restrict__ A, const unsigned short* __restrict__ B,
    unsigned short* __restrict__ out,
    const int* __restrict__ offs, const int* __restrict__ atok,
    const float* __restrict__ agate) {
    constexpr int KD = MODE == 0 ? DDIM : HDIM;
    constexpr int NC = MODE == 0 ? HDIM : DDIM;
    const int e = blockIdx.z;
    const int m0 = offs[e];
    const int mE = offs[e + 1] - m0;
    const int tm = blockIdx.y;
    if (tm * 128 >= mE) return;
    const int n0 = blockIdx.x * 128;

    __shared__ __align__(16) unsigned short As_[2][128 * 32];   // 8 KiB each
    __shared__ __align__(16) unsigned short Bs_[2][128 * 32];   // total 32 KiB

    const int tid = threadIdx.x, lane = tid & 63;
    const int wid = tid >> 6, wm = wid >> 1, wn = wid & 1;

    // ---- staging descriptors (pre-swizzled global sources) ----
    // chunk c in 0..511: row = c>>2 (0..127), slot = c&3 (16B within 64B row)
    const unsigned short* sA[2];
    const unsigned short* sB[2];
    int dOff[2];
#pragma unroll
    for (int it = 0; it < 2; ++it) {
        int c = tid + it * 256;
        int row = c >> 2, slot = c & 3;
        int ksw = (slot ^ ((row >> 1) & 3)) * 8;   // pre-swizzled k-chunk
        int arow = tm * 128 + row; arow = arow < mE ? arow : mE - 1;
        if (MODE == 0)
            sA[it] = A + (size_t)atok[m0 + arow] * KD + ksw;
        else
            sA[it] = A + (size_t)(m0 + arow) * KD + ksw;
        sB[it] = B + (size_t)e * KD * NC + (size_t)(n0 + row) * KD + ksw;
        dOff[it] = c * 16;
    }

    f32x4 acc[4][4] = {};

    auto stage = [&](int b, int kk) {
        gld16((char*)As_[b] + dOff[0], sA[0] + kk);
        gld16((char*)As_[b] + dOff[1], sA[1] + kk);
        gld16((char*)Bs_[b] + dOff[0], sB[0] + kk);
        gld16((char*)Bs_[b] + dOff[1], sB[1] + kk);
    };
    auto compute = [&](int b) {
        const int c16 = lane & 15, q = lane >> 4;
        bf16x8 av[4], bv[4];
#pragma unroll
        for (int mi = 0; mi < 4; ++mi) {
            int r = wm * 64 + mi * 16 + c16;
            int s = q ^ ((r >> 1) & 3);
            av[mi] = *(const bf16x8*)((const char*)As_[b] + r * 64 + s * 16);
        }
#pragma unroll
        for (int ni = 0; ni < 4; ++ni) {
            int r = wn * 64 + ni * 16 + c16;
            int s = q ^ ((r >> 1) & 3);
            bv[ni] = *(const bf16x8*)((const char*)Bs_[b] + r * 64 + s * 16);
        }
#pragma unroll
        for (int mi = 0; mi < 4; ++mi)
#pragma unroll
            for (int ni = 0; ni < 4; ++ni)
                acc[mi][ni] = __builtin_amdgcn_mfma_f32_16x16x32_bf16(
                    av[mi], bv[ni], acc[mi][ni], 0, 0, 0);
    };

    // prologue: fill buffer 0
    stage(0, 0);
    __syncthreads();

#pragma unroll 1
    for (int kk = 0; kk < KD; kk += 64) {
        stage(1, kk + 32);          // kk+32 < KD always (KD % 64 == 0)
        compute(0);
        __syncthreads();            // drains stage(1) + all reads of buf0 done
        if (kk + 64 < KD) stage(0, kk + 64);
        compute(1);
        __syncthreads();
    }

    // epilogue: C/D layout col = lane&15, row = (lane>>4)*4 + reg
    const int col = lane & 15, r4 = (lane >> 4) * 4;
#pragma unroll
    for (int mi = 0; mi < 4; ++mi) {
#pragma unroll
        for (int r = 0; r < 4; ++r) {
            int grow = tm * 128 + wm * 64 + mi * 16 + r4 + r;
            if (grow >= mE) continue;
            float gate = (MODE == 0) ? agate[m0 + grow] : 0.0f;
#pragma unroll
            for (int ni = 0; ni < 4; ++ni) {
                int gcol = n0 + wn * 64 + ni * 16 + col;
                float v = acc[mi][ni][r];
                if (MODE == 0)
                    out[(size_t)(m0 + grow) * NC + gcol] = f2bf(gelu_f(v) * gate);
                else
                    out[(size_t)(m0 + grow) * NC + gcol] = f2bf(v);
            }
        }
    }
}

// ---------------------------------------------------------------------------
extern "C" void kernel_launch(void* const* d_in, const int* in_sizes, int n_in,
                              void* d_out, int out_size, void* d_ws, size_t ws_size,
                              hipStream_t stream) {
    const float* x   = (const float*)d_in[0];
    const float* Wr  = (const float*)d_in[1];
    const float* Wg  = (const float*)d_in[2];
    const float* W1  = (const float*)d_in[3];
    const float* W2  = (const float*)d_in[4];
    const float* W1s = (const float*)d_in[5];
    const float* W2s = (const float*)d_in[6];
    float* out = (float*)d_out;

    char* ws = (char*)d_ws;
    size_t off = 0;
    auto carve = [&](size_t bytes) { char* p = ws + off; off += (bytes + 255) & ~(size_t)255; return p; };
    // NOTE: contrib (NROWS x DDIM bf16 = 96 MiB) aliases [xb, w1all] (100 MiB),
    // both dead after gemm128<0>; stream order serializes the reuse.
    unsigned short* xb    = (unsigned short*)carve((size_t)N_TOK * DDIM * 2);            // 32 MiB
    unsigned short* w1all = (unsigned short*)carve((size_t)(NEXP + 1) * DDIM * HDIM * 2);// 68 MiB
    unsigned short* w2all = (unsigned short*)carve((size_t)(NEXP + 1) * HDIM * DDIM * 2);// 68 MiB
    unsigned short* hb    = (unsigned short*)carve((size_t)NROWS * HDIM * 2);            // 48 MiB
    float* gsh            = (float*)carve((size_t)N_TOK * 4);
    int* t2i              = (int*)carve((size_t)N_TOK * 2 * 4);
    float* t2v            = (float*)carve((size_t)N_TOK * 2 * 4);
    int* atok             = (int*)carve((size_t)NROWS * 4);
    float* agate          = (float*)carve((size_t)NROWS * 4);
    int* t2pos            = (int*)carve((size_t)NASSIGN * 4);
    float* imp            = (float*)carve(256);
    int* offs             = (int*)carve(256);
    int* fill             = (int*)carve(256);
    if (ws_size < off) return;   // fail loudly (output stays invalid)

    unsigned short* contrib = (unsigned short*)ws;   // alias over xb+w1all

    float* out_tail = out + (size_t)N_TOK * DDIM;

    hipLaunchKernelGGL(zero_small, dim3(1), dim3(256), 0, stream, imp);
    // weights, transposed to B^T[NC][KD]; shared expert = z slice 16
    hipLaunchKernelGGL((transpose_cast<DDIM, HDIM>), dim3(HDIM / 64, DDIM / 64, NEXP + 1), dim3(256), 0, stream,
                       W1, W1s, w1all);
    hipLaunchKernelGGL((transpose_cast<HDIM, DDIM>), dim3(DDIM / 64, HDIM / 64, NEXP + 1), dim3(256), 0, stream,
                       W2, W2s, w2all);
    // router also writes xb (bf16 cast of x, one pass)
    hipLaunchKernelGGL(router_kernel, dim3(N_TOK / 4), dim3(256), 0, stream, x, Wr, Wg, xb, gsh, t2i, t2v, imp);
    hipLaunchKernelGGL(scan_finalize, dim3(1), dim3(256), 0, stream, t2i, imp, offs, fill, out_tail);
    hipLaunchKernelGGL(build_assign, dim3(N_TOK / 256), dim3(256), 0, stream, t2i, t2v, offs, fill, gsh, atok, agate, t2pos);

    // grouped L1 (17 groups incl. shared): xb -> hb
    hipLaunchKernelGGL((gemm128<0>), dim3(HDIM / 128, N_TOK / 128, NEXP + 1), dim3(256), 0, stream,
                       xb, w1all, hb, offs, atok, agate);
    // grouped L2: hb -> contrib (overwrites xb/w1all region)
    hipLaunchKernelGGL((gemm128<1>), dim3(DDIM / 128, N_TOK / 128, NEXP + 1), dim3(256), 0, stream,
                       hb, w2all, contrib, offs, atok, agate);
    // y[n] = contrib[p0] + contrib[p1] + contrib[shared] (gsh folded into L1 gate)
    hipLaunchKernelGGL(combine_kernel, dim3(N_TOK * DDIM / 8 / 256), dim3(256), 0, stream,
                       contrib, t2pos, out);
}